// Round 10
// baseline (359.660 us; speedup 1.0000x reference)
//
#include <hip/hip_runtime.h>
#include <cmath>

// RestorationLoss = (1 - mean(SSIM(r_low, r_high))) + mean((r_low - r_high)^2)
// Separable 11x11 gaussian; 4 conv fields: mu1, mu2, S=conv(a^2+b^2), P=conv(ab).
// out = 1 + sum(d^2 - ssim_px)/N.
// R10: vertical-marching ring buffer. Each block: 64-col x 64-row strip,
// 4 sub-tiles of 16 rows. h-conv each input row EXACTLY once (R8/R9 tiles
// re-conv'd 10/26 rows), ring hbuf[4][32][64] planar (0-conflict proven).
// Prefetch next sub-tile's 16 rows into regs before phase 2 (hides HBM
// latency under vertical conv); t-loop fully unrolled so ring slots fold.
// Frozen: 256 thr, launch_bounds(256,3) (tight caps spill: R5/R7), planar LDS.

#define HH 512
#define WW 512
#define TILE_W 64
#define RING 32                               // >= 11 window + 16 stage + slack
#define NPLANES 48
#define CT (WW / TILE_W)                      // 8 col strips
#define GT 8                                  // row groups (64 rows each)
#define NBLOCKS (NPLANES * GT * CT)           // 3072

struct GW { float g[11]; };

__global__ __launch_bounds__(256, 3)
void ssim_main(const float* __restrict__ img1, const float* __restrict__ img2,
               float* __restrict__ partial, GW gw)
{
    __shared__ float hbuf[4][RING][TILE_W];   // planar ring: 32768 B
    __shared__ float red[4];

    const int tid   = threadIdx.x;
    const int bx    = blockIdx.x;             // col strip 0..7
    const int gy    = blockIdx.y;             // row group 0..7
    const int plane = blockIdx.z;
    const int base  = gy * 64;                // first output row of strip
    const int col0  = bx * TILE_W;
    const float* p1 = img1 + (size_t)plane * (HH * WW);
    const float* p2 = img2 + (size_t)plane * (HH * WW);

    const int  cg    = tid & 15;              // col group: tile cols 4cg..4cg+3
    const int  rs    = tid >> 4;              // row slot 0..15
    const int  cbase = col0 + 4 * cg - 8;     // 20-float window, 16B aligned
    const bool colok = (cbase >= 0) && (cbase + 20 <= WW);

    // issue global loads for input row `grow` (clamped; mask applied at store)
    auto loadRow = [&](int grow, float* x1, float* x2) {
        const int growc = min(max(grow, 0), HH - 1);
        const float* r1 = p1 + (size_t)growc * WW;
        const float* r2 = p2 + (size_t)growc * WW;
        if (colok) {
            const float4* q1 = reinterpret_cast<const float4*>(r1 + cbase);
            const float4* q2 = reinterpret_cast<const float4*>(r2 + cbase);
            #pragma unroll
            for (int v = 0; v < 5; ++v) {
                float4 a = q1[v], b = q2[v];
                x1[4*v+0] = a.x; x1[4*v+1] = a.y; x1[4*v+2] = a.z; x1[4*v+3] = a.w;
                x2[4*v+0] = b.x; x2[4*v+1] = b.y; x2[4*v+2] = b.z; x2[4*v+3] = b.w;
            }
        } else {                              // col-edge threads only
            #pragma unroll
            for (int e = 0; e < 20; ++e) {
                int   gc  = cbase + e;
                int   gcc = min(max(gc, 0), WW - 1);
                float m   = (gc >= 0 && gc < WW) ? 1.f : 0.f;
                x1[e] = r1[gcc] * m;
                x2[e] = r2[gcc] * m;
            }
        }
    };

    // horizontal conv of one input row -> ring slot (grow+5)&31
    auto convStore = [&](int grow, const float* x1, const float* x2) {
        const float rmask = (grow >= 0 && grow < HH) ? 1.f : 0.f;
        const int   slot  = (grow + 5) & (RING - 1);
        float acc[4][4];
        #pragma unroll
        for (int k = 0; k < 4; ++k)
            #pragma unroll
            for (int i = 0; i < 4; ++i) acc[k][i] = 0.f;
        #pragma unroll
        for (int e = 3; e <= 16; ++e) {       // out col i uses e = i+j+3
            float a  = x1[e], b = x2[e];
            float v2 = a * a + b * b;
            float v3 = a * b;
            #pragma unroll
            for (int i = 0; i < 4; ++i) {
                int j = e - 3 - i;
                if (j >= 0 && j < 11) {
                    float w = gw.g[j];
                    acc[0][i] += w * a;
                    acc[1][i] += w * b;
                    acc[2][i] += w * v2;
                    acc[3][i] += w * v3;
                }
            }
        }
        // row-OOB rows contribute zero (all 4 fields vanish on zero inputs)
        #pragma unroll
        for (int k = 0; k < 4; ++k)
            *reinterpret_cast<float4*>(&hbuf[k][slot][4 * cg]) =
                make_float4(acc[k][0] * rmask, acc[k][1] * rmask,
                            acc[k][2] * rmask, acc[k][3] * rmask);
    };

    // ---- init: stage rows [base-5, base+20] (26 rows, R9-style pipelined) ----
    {
        float xA1[20], xA2[20], xB1[20], xB2[20];
        loadRow(base - 5 + rs, xA1, xA2);
        loadRow(base + 11 + rs, xB1, xB2);    // issued early; only rs<10 stored
        convStore(base - 5 + rs, xA1, xA2);
        if (rs < 10) convStore(base + 11 + rs, xB1, xB2);
    }
    __syncthreads();

    // ---- march 4 sub-tiles of 16 output rows ----
    const int tx = tid & 63;                  // column
    const int rg = tid >> 6;                  // 0..3 -> 4 output rows each
    float local = 0.f;
    const float C1c = 0.0001f, C2c = 0.0009f;

    #pragma unroll
    for (int t = 0; t < 4; ++t) {
        const int r0 = base + 16 * t;

        // prefetch next sub-tile's input row (loads in flight during phase 2)
        float nx1[20], nx2[20];
        if (t < 3) loadRow(r0 + 21 + rs, nx1, nx2);

        // vertical conv + ssim + mse for rows r0 .. r0+15
        {
            float res[4][4];                  // [field][p]
            #pragma unroll
            for (int k = 0; k < 4; ++k) {
                float win[14];
                #pragma unroll
                for (int tt = 0; tt < 14; ++tt)
                    win[tt] = hbuf[k][(r0 + 4 * rg + tt) & (RING - 1)][tx];
                #pragma unroll
                for (int p = 0; p < 4; ++p) {
                    float s = 0.f;
                    #pragma unroll
                    for (int j = 0; j < 11; ++j) s += gw.g[j] * win[p + j];
                    res[k][p] = s;
                }
            }
            #pragma unroll
            for (int p = 0; p < 4; ++p) {
                float mu1 = res[0][p], mu2 = res[1][p];
                float S   = res[2][p], P   = res[3][p];
                float m11 = mu1 * mu1, m22 = mu2 * mu2, m12 = mu1 * mu2;
                float num = (2.f * m12 + C1c) * (2.f * (P - m12) + C2c);
                float den = (m11 + m22 + C1c) * ((S - m11 - m22) + C2c);
                size_t off = (size_t)(r0 + 4 * rg + p) * WW + col0 + tx;
                float a = p1[off], b = p2[off];
                float d = a - b;
                local += d * d - num / den;
            }
        }
        __syncthreads();                      // ring reads done
        if (t < 3) convStore(base + 16 * t + 21 + rs, nx1, nx2); // dead slots
        __syncthreads();                      // writes visible
    }

    // ---- block reduce ----
    #pragma unroll
    for (int off = 32; off > 0; off >>= 1) local += __shfl_down(local, off);
    if ((tid & 63) == 0) red[tid >> 6] = local;
    __syncthreads();
    if (tid == 0) {
        int bid = (plane * GT + gy) * CT + bx;
        partial[bid] = (red[0] + red[1]) + (red[2] + red[3]);
    }
}

__global__ __launch_bounds__(256)
void ssim_finish(const float* __restrict__ partial, float* __restrict__ out)
{
    __shared__ float red[256];
    float s = 0.f;
    #pragma unroll
    for (int i = 0; i < NBLOCKS / 256; ++i)   // 12 independent loads in flight
        s += partial[i * 256 + threadIdx.x];
    red[threadIdx.x] = s;
    __syncthreads();
    for (int step = 128; step > 0; step >>= 1) {
        if ((int)threadIdx.x < step) red[threadIdx.x] += red[threadIdx.x + step];
        __syncthreads();
    }
    if (threadIdx.x == 0)
        out[0] = 1.0f + red[0] * (1.0f / 12582912.0f);
}

extern "C" void kernel_launch(void* const* d_in, const int* in_sizes, int n_in,
                              void* d_out, int out_size, void* d_ws, size_t ws_size,
                              hipStream_t stream)
{
    const float* r_low  = (const float*)d_in[0];
    const float* r_high = (const float*)d_in[1];
    float* out     = (float*)d_out;
    float* partial = (float*)d_ws;                   // 3072 floats = 12 KB

    GW gw;                                           // gaussian -> SGPRs
    {
        float s = 0.f;
        for (int i = 0; i < 11; ++i) {
            float c = (float)(i - 5);
            gw.g[i] = expf(-(c * c) / 4.5f);         // 2*sigma^2 = 4.5
            s += gw.g[i];
        }
        for (int i = 0; i < 11; ++i) gw.g[i] /= s;
    }

    dim3 grid(CT, GT, NPLANES);
    ssim_main<<<grid, dim3(256), 0, stream>>>(r_low, r_high, partial, gw);
    ssim_finish<<<1, dim3(256), 0, stream>>>(partial, out);
}

// Round 11
// 172.065 us; speedup vs baseline: 2.0903x; 2.0903x over previous
//
#include <hip/hip_runtime.h>
#include <cmath>

// RestorationLoss = (1 - mean(SSIM(r_low, r_high))) + mean((r_low - r_high)^2)
// Separable 11x11 gaussian; 4 conv fields: mu1, mu2, S=conv(a^2+b^2), P=conv(ab).
// out = 1 + sum(d^2 - ssim_px)/N.
// R11 = R9 skeleton (best: 125us, 0 spills) + three targeted cuts:
//  (a) interleaved PADDED hbuf[26][65] float4: phase-2 = 14 ds_read_b128
//      (was 56 b32). Bank math: reads 8 start-banks (conflict-free), writes
//      2-way aliased (free, m136). R5's conflicts came from UNPADDED stride.
//  (b) ssim via v_rcp_f32 (num*rcp(den)): drops ~10 instr/px incl slow-rate
//      div ops; rel err 1e-7 << 2.3e-2 threshold.
//  (c) edge path: OOB col spans are float4-aligned -> 5 conditional float4
//      loads w/ zero-fill, no divergent 40-scalar-load path, no col masks.
// Frozen: 256 thr, launch_bounds(256,3) (R5/R7: tight caps spill; R10: no
// register arrays live across barriers), TILE_H=16, R9 load pipeline.

#define HH 512
#define WW 512
#define TILE_H 16
#define TILE_W 64
#define HB (TILE_H + 10)                          // 26 staged rows
#define LDW 65                                    // padded row: 65 float4s
#define NPLANES 48
#define CT (WW / TILE_W)                          // 8
#define RT (HH / TILE_H)                          // 32
#define NBLOCKS (NPLANES * RT * CT)               // 12288

struct GW { float g[11]; };

__global__ __launch_bounds__(256, 3)              // VGPR cap ~170: allocator free
void ssim_main(const float* __restrict__ img1, const float* __restrict__ img2,
               float* __restrict__ partial, GW gw)
{
    __shared__ float4 hbuf[HB][LDW];              // interleaved (mu1,mu2,S,P): 27040 B
    __shared__ float red[4];

    const int tid   = threadIdx.x;
    const int bx    = blockIdx.x;
    const int by    = blockIdx.y;
    const int plane = blockIdx.z;
    const int row0  = by * TILE_H;
    const int col0  = bx * TILE_W;
    const float* p1 = img1 + (size_t)plane * (HH * WW);
    const float* p2 = img2 + (size_t)plane * (HH * WW);

    const int cg    = tid & 15;                   // col group: tile cols 4cg..4cg+3
    const int rs    = tid >> 4;                   // 0..15
    const int cbase = col0 + 4 * cg - 8;          // 20-float window, 16B aligned

    // 5 conditional float4 loads; OOB vectors become zeros (valid: all OOB col
    // spans are float4-aligned since cbase%4==0 and limits 0/512 are too)
    auto loadRow = [&](int grow, float4* x1, float4* x2) {
        const int growc = min(max(grow, 0), HH - 1);      // always in-bounds
        const float* r1 = p1 + (size_t)growc * WW;
        const float* r2 = p2 + (size_t)growc * WW;
        #pragma unroll
        for (int v = 0; v < 5; ++v) {
            const int c0 = cbase + 4 * v;
            if (c0 >= 0 && c0 + 4 <= WW) {
                x1[v] = *reinterpret_cast<const float4*>(r1 + c0);
                x2[v] = *reinterpret_cast<const float4*>(r2 + c0);
            } else {
                x1[v] = make_float4(0.f, 0.f, 0.f, 0.f);
                x2[v] = make_float4(0.f, 0.f, 0.f, 0.f);
            }
        }
    };

    // horizontal conv of one staged row -> interleaved hbuf[rl][col]
    auto convStore = [&](int rl, const float4* x1v, const float4* x2v) {
        const int   grow  = row0 - 5 + rl;
        const float rmask = (grow >= 0 && grow < HH) ? 1.f : 0.f;
        const float* x1 = reinterpret_cast<const float*>(x1v);
        const float* x2 = reinterpret_cast<const float*>(x2v);
        float acc[4][4];
        #pragma unroll
        for (int k = 0; k < 4; ++k)
            #pragma unroll
            for (int i = 0; i < 4; ++i) acc[k][i] = 0.f;
        #pragma unroll
        for (int e = 3; e <= 16; ++e) {           // out col i uses e = i+j+3
            float a  = x1[e], b = x2[e];
            float v2 = a * a + b * b;
            float v3 = a * b;
            #pragma unroll
            for (int i = 0; i < 4; ++i) {
                int j = e - 3 - i;
                if (j >= 0 && j < 11) {
                    float w = gw.g[j];
                    acc[0][i] += w * a;
                    acc[1][i] += w * b;
                    acc[2][i] += w * v2;
                    acc[3][i] += w * v3;
                }
            }
        }
        // row-OOB rows contribute zero (all 4 fields vanish on zero inputs)
        #pragma unroll
        for (int i = 0; i < 4; ++i)
            hbuf[rl][4 * cg + i] =
                make_float4(acc[0][i] * rmask, acc[1][i] * rmask,
                            acc[2][i] * rmask, acc[3][i] * rmask);
    };

    // ---- Phase 1: software-pipelined (R9): both rows' loads in flight ----
    {
        float4 xA1[5], xA2[5], xB1[5], xB2[5];
        loadRow(row0 - 5 + rs, xA1, xA2);         // rows 0..15
        loadRow(row0 + 11 + rs, xB1, xB2);        // rows 16..31 (clamped, safe)
        convStore(rs, xA1, xA2);                  // under B's load latency
        if (rs < 10)                              // only rows 16..25 staged
            convStore(rs + 16, xB1, xB2);
    }

    // ---- MSE pixel prefetch (no LDS dependence; consumed after barrier) ----
    const int tx = tid & 63;                      // column
    const int rg = tid >> 6;                      // 0..3 -> rows 4rg..4rg+3
    float mse_a[4], mse_b[4];
    #pragma unroll
    for (int p = 0; p < 4; ++p) {
        size_t off = (size_t)(row0 + rg * 4 + p) * WW + col0 + tx;
        mse_a[p] = p1[off];
        mse_b[p] = p2[off];
    }
    __syncthreads();

    // ---- Phase 2: vertical conv (14 b128 reads) + ssim + mse ----
    float local = 0.f;
    {
        float4 res[4];
        #pragma unroll
        for (int p = 0; p < 4; ++p) res[p] = make_float4(0.f, 0.f, 0.f, 0.f);
        #pragma unroll
        for (int j = 0; j < 14; ++j) {            // window rows rg*4 .. rg*4+13
            float4 w4 = hbuf[rg * 4 + j][tx];
            #pragma unroll
            for (int p = 0; p < 4; ++p) {
                int t = j - p;
                if (t >= 0 && t < 11) {
                    float w = gw.g[t];
                    res[p].x += w * w4.x;
                    res[p].y += w * w4.y;
                    res[p].z += w * w4.z;
                    res[p].w += w * w4.w;
                }
            }
        }
        const float C1c = 0.0001f, C2c = 0.0009f;
        #pragma unroll
        for (int p = 0; p < 4; ++p) {
            float mu1 = res[p].x, mu2 = res[p].y;
            float S   = res[p].z, P   = res[p].w;
            float m11 = mu1 * mu1, m22 = mu2 * mu2, m12 = mu1 * mu2;
            float num = (2.f * m12 + C1c) * (2.f * (P - m12) + C2c);
            float den = (m11 + m22 + C1c) * ((S - m11 - m22) + C2c);
            float inv = __builtin_amdgcn_rcpf(den);   // ~1ulp, fine vs 2.3e-2
            float d   = mse_a[p] - mse_b[p];
            local += d * d - num * inv;
        }
    }

    // ---- block reduce ----
    #pragma unroll
    for (int off = 32; off > 0; off >>= 1) local += __shfl_down(local, off);
    if ((tid & 63) == 0) red[tid >> 6] = local;
    __syncthreads();
    if (tid == 0) {
        int bid = (plane * RT + by) * CT + bx;
        partial[bid] = (red[0] + red[1]) + (red[2] + red[3]);
    }
}

__global__ __launch_bounds__(256)
void ssim_finish(const float* __restrict__ partial, float* __restrict__ out)
{
    __shared__ float red[256];
    float s = 0.f;
    #pragma unroll
    for (int i = 0; i < NBLOCKS / 256; ++i)       // 48 independent loads
        s += partial[i * 256 + threadIdx.x];
    red[threadIdx.x] = s;
    __syncthreads();
    for (int step = 128; step > 0; step >>= 1) {
        if ((int)threadIdx.x < step) red[threadIdx.x] += red[threadIdx.x + step];
        __syncthreads();
    }
    if (threadIdx.x == 0)
        out[0] = 1.0f + red[0] * (1.0f / 12582912.0f);
}

extern "C" void kernel_launch(void* const* d_in, const int* in_sizes, int n_in,
                              void* d_out, int out_size, void* d_ws, size_t ws_size,
                              hipStream_t stream)
{
    const float* r_low  = (const float*)d_in[0];
    const float* r_high = (const float*)d_in[1];
    float* out     = (float*)d_out;
    float* partial = (float*)d_ws;                       // 12288 floats = 48 KB

    GW gw;                                               // gaussian -> SGPRs
    {
        float s = 0.f;
        for (int i = 0; i < 11; ++i) {
            float c = (float)(i - 5);
            gw.g[i] = expf(-(c * c) / 4.5f);             // 2*sigma^2 = 4.5
            s += gw.g[i];
        }
        for (int i = 0; i < 11; ++i) gw.g[i] /= s;
    }

    dim3 grid(CT, RT, NPLANES);
    ssim_main<<<grid, dim3(256), 0, stream>>>(r_low, r_high, partial, gw);
    ssim_finish<<<1, dim3(256), 0, stream>>>(partial, out);
}